// Round 5
// baseline (352.848 us; speedup 1.0000x reference)
//
#include <hip/hip_runtime.h>
#include <hip/hip_bf16.h>

// MaxPool4d: x[4,16,16,16,64,64] f32, window 2 stride 2 over trailing 4 dims.
// Output [4,16,8,8,32,32] f32.
//
// Pure streaming reduction: each thread loads 8 float4 (2x2x2 over k,d,h;
// float4 spans 4 W elems = 2 output W elems), reduces, stores one float2.
//
// Index decomposition (all pow2, shifts only):
//   idx = ((((nc*8 + k)*8 + d)*32 + h)*16 + tw),  total = 64*8*8*32*16 = 2^21
//   input base = nc<<20 | (2k)<<16 | (2d)<<12 | (2h)<<6 | tw<<2

#define IN_NC_SHIFT 20   // 16*16*64*64 = 1048576
#define IN_K_STRIDE 65536
#define IN_D_STRIDE 4096
#define IN_H_STRIDE 64

__global__ __launch_bounds__(256) void maxpool4d_kernel(
    const float* __restrict__ x, float2* __restrict__ out, int total) {
    int idx = blockIdx.x * blockDim.x + threadIdx.x;
    if (idx >= total) return;

    // decompose
    int tw = idx & 15;          // W chunk (4 input floats)
    int h  = (idx >> 4) & 31;   // output h
    int d  = (idx >> 9) & 7;    // output d
    int k  = (idx >> 12) & 7;   // output k
    int nc = idx >> 15;         // fused n*c, [0,64)

    const float* p = x + ((size_t)nc << IN_NC_SHIFT)
                       + ((size_t)(k << 1) * IN_K_STRIDE)
                       + ((size_t)(d << 1) * IN_D_STRIDE)
                       + ((size_t)(h << 1) * IN_H_STRIDE)
                       + ((size_t)tw << 2);

    float4 v0 = *(const float4*)(p);
    float4 v1 = *(const float4*)(p + IN_H_STRIDE);
    float4 v2 = *(const float4*)(p + IN_D_STRIDE);
    float4 v3 = *(const float4*)(p + IN_D_STRIDE + IN_H_STRIDE);
    float4 v4 = *(const float4*)(p + IN_K_STRIDE);
    float4 v5 = *(const float4*)(p + IN_K_STRIDE + IN_H_STRIDE);
    float4 v6 = *(const float4*)(p + IN_K_STRIDE + IN_D_STRIDE);
    float4 v7 = *(const float4*)(p + IN_K_STRIDE + IN_D_STRIDE + IN_H_STRIDE);

    float4 m;
    m.x = fmaxf(fmaxf(fmaxf(v0.x, v1.x), fmaxf(v2.x, v3.x)),
                fmaxf(fmaxf(v4.x, v5.x), fmaxf(v6.x, v7.x)));
    m.y = fmaxf(fmaxf(fmaxf(v0.y, v1.y), fmaxf(v2.y, v3.y)),
                fmaxf(fmaxf(v4.y, v5.y), fmaxf(v6.y, v7.y)));
    m.z = fmaxf(fmaxf(fmaxf(v0.z, v1.z), fmaxf(v2.z, v3.z)),
                fmaxf(fmaxf(v4.z, v5.z), fmaxf(v6.z, v7.z)));
    m.w = fmaxf(fmaxf(fmaxf(v0.w, v1.w), fmaxf(v2.w, v3.w)),
                fmaxf(fmaxf(v4.w, v5.w), fmaxf(v6.w, v7.w)));

    float2 o;
    o.x = fmaxf(m.x, m.y);
    o.y = fmaxf(m.z, m.w);
    out[idx] = o;
}

extern "C" void kernel_launch(void* const* d_in, const int* in_sizes, int n_in,
                              void* d_out, int out_size, void* d_ws, size_t ws_size,
                              hipStream_t stream) {
    const float* x = (const float*)d_in[0];
    float2* out = (float2*)d_out;
    int total = out_size / 2;  // 2,097,152 float2 units
    int block = 256;
    int grid = (total + block - 1) / block;  // 8192 blocks
    maxpool4d_kernel<<<grid, block, 0, stream>>>(x, out, total);
}